// Round 1
// baseline (392.058 us; speedup 1.0000x reference)
//
#include <hip/hip_runtime.h>
#include <stdint.h>

typedef __bf16 bf16x8 __attribute__((ext_vector_type(8)));
typedef float f32x4 __attribute__((ext_vector_type(4)));
typedef unsigned short us8 __attribute__((ext_vector_type(8)));
typedef unsigned short us4 __attribute__((ext_vector_type(4)));

#define DD 128      // feature dim
#define TILE 64     // edges per block-tile
#define LSTR 136    // LDS row stride in ushorts (even bank spread for b128 frag reads)

__device__ __forceinline__ unsigned short f2bf(float f) {
    unsigned int u = __builtin_bit_cast(unsigned int, f);
    u += 0x7FFFu + ((u >> 16) & 1u);   // RNE; inputs finite
    return (unsigned short)(u >> 16);
}
__device__ __forceinline__ float bf2f(unsigned short s) {
    return __builtin_bit_cast(float, ((unsigned int)s) << 16);
}

__global__ void fill_zero(unsigned int* __restrict__ p, long n) {
    long i = (long)blockIdx.x * blockDim.x + threadIdx.x;
    long stride = (long)gridDim.x * blockDim.x;
    long n4 = n >> 2;
    uint4* p4 = (uint4*)p;
    for (long k = i; k < n4; k += stride) p4[k] = make_uint4(0u, 0u, 0u, 0u);
    for (long k = (n4 << 2) + i; k < n; k += stride) p[k] = 0u;
}

__device__ __forceinline__ float dec1(unsigned int u) {
    float z = (float)(u & 0x1FFFFu) * (1.0f / 2048.0f) - 36.0f;
    float s = 1.0f / (1.0f + __expf(-z));
    return __logf(s + 1e-10f);
}

__global__ void decode_log(unsigned int* __restrict__ p, long n) {
    long i = (long)blockIdx.x * blockDim.x + threadIdx.x;
    long stride = (long)gridDim.x * blockDim.x;
    long n4 = n >> 2;
    for (long k = i; k < n4; k += stride) {
        uint4 u = ((uint4*)p)[k];
        float4 r;
        r.x = dec1(u.x); r.y = dec1(u.y); r.z = dec1(u.z); r.w = dec1(u.w);
        ((float4*)p)[k] = r;
    }
    for (long k = (n4 << 2) + i; k < n; k += stride) {
        unsigned int u = p[k];
        ((float*)p)[k] = dec1(u);
    }
}

// Block: 256 threads = 4 waves. Tile: 64 edges x 128 features, K=128.
// Wave w owns output features [32w, 32w+32) for both layers (2 N-tiles of 16).
// Weights kept in registers as MFMA B-fragments; edge tile staged in LDS as bf16.
__global__ __launch_bounds__(256)
void mlp_scatter(const float* __restrict__ A,
                 const int* __restrict__ eidx,
                 const float* __restrict__ W1, const float* __restrict__ B1,
                 const float* __restrict__ W2, const float* __restrict__ B2,
                 const float* __restrict__ WO, const float* __restrict__ BO,
                 const int* __restrict__ NN_p,
                 unsigned int* __restrict__ out,
                 int E, int numTiles)
{
    __shared__ unsigned short Abuf[TILE][LSTR];  // edge_attr bf16, later reused for H2
    __shared__ unsigned short Hbuf[TILE][LSTR];  // H1 bf16
    __shared__ float wout_s[DD];

    const int tid  = threadIdx.x;
    const int lane = tid & 63;
    const int wave = tid >> 6;
    const int lrow = lane & 15;          // A-frag row / B-frag (=D) col
    const int lk   = (lane >> 4) * 8;    // k base within a 32-chunk

    if (tid < DD) wout_s[tid] = WO[tid];

    // Load weight B-fragments: B[k][f] = W[f][k] -> lane reads W[f][kb..kb+7]
    bf16x8 w1f[2][4], w2f[2][4];
    float bw1[2], bw2[2];
    #pragma unroll
    for (int n = 0; n < 2; ++n) {
        int f = wave * 32 + n * 16 + lrow;
        bw1[n] = B1[f];
        bw2[n] = B2[f];
        #pragma unroll
        for (int kk = 0; kk < 4; ++kk) {
            int kb = kk * 32 + lk;
            const float* p1 = W1 + f * DD + kb;
            const float* p2 = W2 + f * DD + kb;
            us8 t1, t2;
            #pragma unroll
            for (int j = 0; j < 8; ++j) { t1[j] = f2bf(p1[j]); t2[j] = f2bf(p2[j]); }
            w1f[n][kk] = __builtin_bit_cast(bf16x8, t1);
            w2f[n][kk] = __builtin_bit_cast(bf16x8, t2);
        }
    }
    const float bo = BO[0];
    const int N = *NN_p;
    const unsigned int NN = (unsigned int)N * (unsigned int)N;

    for (int t = blockIdx.x; t < numTiles; t += gridDim.x) {
        const long r0 = (long)t * TILE;
        __syncthreads();  // prev iter's z-phase reads of Abuf done

        // ---- stage edge_attr tile: fp32 -> bf16 LDS (coalesced float4) ----
        {
            const float4* src = (const float4*)(A + r0 * DD);
            #pragma unroll
            for (int s = 0; s < 8; ++s) {
                int id  = s * 256 + tid;     // 2048 float4 units = 64 rows x 32
                int row = id >> 5;
                int c4  = (id & 31) * 4;
                float4 v = src[id];
                us4 o;
                o[0] = f2bf(v.x); o[1] = f2bf(v.y); o[2] = f2bf(v.z); o[3] = f2bf(v.w);
                *(us4*)&Abuf[row][c4] = o;
            }
        }
        __syncthreads();

        // ---- layer 1: H1 = silu(A @ W1^T + b1) ----
        f32x4 acc1[4][2];
        #pragma unroll
        for (int m = 0; m < 4; ++m)
            #pragma unroll
            for (int n = 0; n < 2; ++n)
                acc1[m][n] = (f32x4){0.f, 0.f, 0.f, 0.f};
        #pragma unroll
        for (int kk = 0; kk < 4; ++kk) {
            bf16x8 af[4];
            #pragma unroll
            for (int m = 0; m < 4; ++m)
                af[m] = __builtin_bit_cast(bf16x8, *(const us8*)&Abuf[m * 16 + lrow][kk * 32 + lk]);
            #pragma unroll
            for (int m = 0; m < 4; ++m)
                #pragma unroll
                for (int n = 0; n < 2; ++n)
                    acc1[m][n] = __builtin_amdgcn_mfma_f32_16x16x32_bf16(af[m], w1f[n][kk], acc1[m][n], 0, 0, 0);
        }
        #pragma unroll
        for (int m = 0; m < 4; ++m)
            #pragma unroll
            for (int n = 0; n < 2; ++n) {
                int f = wave * 32 + n * 16 + lrow;
                #pragma unroll
                for (int i = 0; i < 4; ++i) {
                    int row = m * 16 + (lane >> 4) * 4 + i;   // D-layout: row=(l>>4)*4+reg
                    float x = acc1[m][n][i] + bw1[n];
                    float h = x / (1.0f + __expf(-x));        // silu
                    Hbuf[row][f] = f2bf(h);
                }
            }
        __syncthreads();

        // ---- layer 2: H2 = silu(H1 @ W2^T + b2), H2 -> Abuf (reuse) ----
        f32x4 acc2[4][2];
        #pragma unroll
        for (int m = 0; m < 4; ++m)
            #pragma unroll
            for (int n = 0; n < 2; ++n)
                acc2[m][n] = (f32x4){0.f, 0.f, 0.f, 0.f};
        #pragma unroll
        for (int kk = 0; kk < 4; ++kk) {
            bf16x8 af[4];
            #pragma unroll
            for (int m = 0; m < 4; ++m)
                af[m] = __builtin_bit_cast(bf16x8, *(const us8*)&Hbuf[m * 16 + lrow][kk * 32 + lk]);
            #pragma unroll
            for (int m = 0; m < 4; ++m)
                #pragma unroll
                for (int n = 0; n < 2; ++n)
                    acc2[m][n] = __builtin_amdgcn_mfma_f32_16x16x32_bf16(af[m], w2f[n][kk], acc2[m][n], 0, 0, 0);
        }
        #pragma unroll
        for (int m = 0; m < 4; ++m)
            #pragma unroll
            for (int n = 0; n < 2; ++n) {
                int f = wave * 32 + n * 16 + lrow;
                #pragma unroll
                for (int i = 0; i < 4; ++i) {
                    int row = m * 16 + (lane >> 4) * 4 + i;
                    float x = acc2[m][n][i] + bw2[n];
                    float h = x / (1.0f + __expf(-x));
                    Abuf[row][f] = f2bf(h);
                }
            }
        __syncthreads();

        // ---- z = Wout . h2 + bout ; pack (e_tag<<17 | qz) ; atomicMax scatter ----
        {
            int e  = tid >> 2;          // 64 edges across 256 threads
            int q4 = tid & 3;           // quarter of D
            int c0 = q4 * 32;
            float zp = 0.f;
            #pragma unroll
            for (int c = 0; c < 4; ++c) {
                us8 hv = *(const us8*)&Abuf[e][c0 + c * 8];
                #pragma unroll
                for (int j = 0; j < 8; ++j)
                    zp += bf2f(hv[j]) * wout_s[c0 + c * 8 + j];
            }
            zp += __shfl_xor(zp, 1);
            zp += __shfl_xor(zp, 2);
            if (q4 == 0) {
                float z = zp + bo;
                long r  = r0 + e;
                int b   = (int)(r / E);
                int ei  = (int)(r - (long)b * E);
                int i0  = eidx[(size_t)(b * 2) * E + ei];
                int j0  = eidx[(size_t)(b * 2 + 1) * E + ei];
                int qz  = (int)((z + 36.0f) * 2048.0f + 0.5f);
                qz = qz < 0 ? 0 : (qz > 131071 ? 131071 : qz);
                unsigned int packed = (((unsigned int)(ei + 1)) << 17) | (unsigned int)qz;
                atomicMax(&out[(size_t)b * NN + (size_t)i0 * N + (size_t)j0], packed);
            }
        }
    }
}

extern "C" void kernel_launch(void* const* d_in, const int* in_sizes, int n_in,
                              void* d_out, int out_size, void* d_ws, size_t ws_size,
                              hipStream_t stream) {
    const float* edge_attr = (const float*)d_in[0];
    const int*   edge_index = (const int*)d_in[1];
    const float* W1   = (const float*)d_in[2];
    const float* b1   = (const float*)d_in[3];
    const float* W2   = (const float*)d_in[4];
    const float* b2   = (const float*)d_in[5];
    const float* Wout = (const float*)d_in[6];
    const float* bout = (const float*)d_in[7];
    const int*   num_nodes = (const int*)d_in[8];

    long rows = (long)in_sizes[0] / DD;        // B*E = 1,024,000
    int  E    = in_sizes[1] / 64;              // B*2*E / 64 with B=32 -> 32000
    int  numTiles = (int)(rows / TILE);        // 16000

    unsigned int* outp = (unsigned int*)d_out;
    long n = (long)out_size;

    fill_zero<<<2048, 256, 0, stream>>>(outp, n);
    mlp_scatter<<<2048, 256, 0, stream>>>(edge_attr, edge_index, W1, b1, W2, b2,
                                          Wout, bout, num_nodes, outp, E, numTiles);
    decode_log<<<2048, 256, 0, stream>>>(outp, n);
}

// Round 2
// 267.439 us; speedup vs baseline: 1.4660x; 1.4660x over previous
//
#include <hip/hip_runtime.h>
#include <stdint.h>
#include <math.h>

typedef __bf16 bf16x8 __attribute__((ext_vector_type(8)));
typedef float f32x4 __attribute__((ext_vector_type(4)));
typedef unsigned short us8 __attribute__((ext_vector_type(8)));
typedef unsigned short us4 __attribute__((ext_vector_type(4)));

#define DD 128      // feature dim
#define TILE 64     // edges per block-tile

__device__ __forceinline__ unsigned short f2bf(float f) {
    __bf16 b = (__bf16)f;                  // native v_cvt (RNE)
    return __builtin_bit_cast(unsigned short, b);
}

__device__ __forceinline__ float fsilu(float x) {
    float e = __expf(-x);
    return x * __builtin_amdgcn_rcpf(1.0f + e);
}

__device__ __forceinline__ float dec1(unsigned int u) {
    float z = (float)(u & 0x1FFFFu) * (1.0f / 2048.0f) - 36.0f;
    float s = __builtin_amdgcn_rcpf(1.0f + __expf(-z));
    return __logf(s + 1e-10f);
}

__global__ void decode_log(unsigned int* __restrict__ p, long n) {
    long i = (long)blockIdx.x * blockDim.x + threadIdx.x;
    long stride = (long)gridDim.x * blockDim.x;
    long n4 = n >> 2;
    for (long k = i; k < n4; k += stride) {
        uint4 u = ((uint4*)p)[k];
        float4 r;
        r.x = dec1(u.x); r.y = dec1(u.y); r.z = dec1(u.z); r.w = dec1(u.w);
        ((float4*)p)[k] = r;
    }
    for (long k = (n4 << 2) + i; k < n; k += stride) {
        unsigned int u = p[k];
        ((float*)p)[k] = dec1(u);
    }
}

// Block: 256 threads = 4 waves. Tile: 64 edges x 128 features, K=128.
// Wave w owns output features [32w, 32w+32) for both hidden layers.
// LDS: two 16 KB bf16 tile buffers, XOR-swizzled (byte ^= (row&7)<<4) so
// ds_read_b128 of per-lane rows at fixed col is bank-conflict-free.
__global__ __launch_bounds__(256)
void mlp_scatter(const float* __restrict__ A,
                 const int* __restrict__ eidx,
                 const float* __restrict__ W1, const float* __restrict__ B1,
                 const float* __restrict__ W2, const float* __restrict__ B2,
                 const float* __restrict__ WO, const float* __restrict__ BO,
                 unsigned int* __restrict__ out,
                 int E, int numTiles, int tpb, int N)
{
    __shared__ unsigned short Abuf[TILE * DD];   // 16 KB: edge_attr bf16, reused for H2
    __shared__ unsigned short Hbuf[TILE * DD];   // 16 KB: H1 bf16

    const int tid  = threadIdx.x;
    const int lane = tid & 63;
    const int wave = tid >> 6;
    const int lrow = lane & 15;          // A-frag row / B-frag col
    const int lkb  = (lane >> 4) * 16;   // byte offset of this lane's 8-bf16 k-slice

    // ---- weight B-fragments in registers: lane holds W[f][kb..kb+7] ----
    bf16x8 w1f[2][4], w2f[2][4], wof[4];
    float bw1[2], bw2[2];
    #pragma unroll
    for (int n = 0; n < 2; ++n) {
        int f = wave * 32 + n * 16 + lrow;
        bw1[n] = B1[f];
        bw2[n] = B2[f];
        #pragma unroll
        for (int kk = 0; kk < 4; ++kk) {
            const float* p1 = W1 + f * DD + kk * 32 + (lane >> 4) * 8;
            const float* p2 = W2 + f * DD + kk * 32 + (lane >> 4) * 8;
            us8 t1, t2;
            #pragma unroll
            for (int j = 0; j < 8; ++j) { t1[j] = f2bf(p1[j]); t2[j] = f2bf(p2[j]); }
            w1f[n][kk] = __builtin_bit_cast(bf16x8, t1);
            w2f[n][kk] = __builtin_bit_cast(bf16x8, t2);
        }
    }
    // Wout broadcast fragment: every lane holds WO[k..k+7] (all 16 B-cols equal
    // -> every output col of the z-MFMA equals z; no lane masking needed)
    #pragma unroll
    for (int kk = 0; kk < 4; ++kk) {
        const float* pw = WO + kk * 32 + (lane >> 4) * 8;
        us8 t;
        #pragma unroll
        for (int j = 0; j < 8; ++j) t[j] = f2bf(pw[j]);
        wof[kk] = __builtin_bit_cast(bf16x8, t);
    }
    const float bo = BO[0];
    const size_t NN = (size_t)N * (size_t)N;

    for (int t = blockIdx.x; t < numTiles; t += gridDim.x) {
        const long r0 = (long)t * TILE;
        __syncthreads();   // prev tile's z-phase reads of Abuf complete

        // ---- stage edge_attr tile: fp32 -> bf16 LDS (coalesced float4) ----
        {
            const float4* src = (const float4*)(A + r0 * DD);
            #pragma unroll
            for (int s = 0; s < 8; ++s) {
                int id  = s * 256 + tid;       // 2048 float4 = 64 rows x 32
                int row = id >> 5;
                int cb  = (id & 31) * 8;       // byte offset (4 ushorts)
                float4 v = src[id];
                us4 o;
                o[0] = f2bf(v.x); o[1] = f2bf(v.y); o[2] = f2bf(v.z); o[3] = f2bf(v.w);
                *(us4*)((char*)Abuf + row * 256 + (cb ^ ((row & 7) << 4))) = o;
            }
        }
        __syncthreads();

        // ---- layer 1: H1 = silu(A @ W1^T + b1) ----
        f32x4 acc1[4][2];
        #pragma unroll
        for (int m = 0; m < 4; ++m)
            #pragma unroll
            for (int n = 0; n < 2; ++n)
                acc1[m][n] = (f32x4){0.f, 0.f, 0.f, 0.f};
        #pragma unroll
        for (int kk = 0; kk < 4; ++kk) {
            bf16x8 af[4];
            #pragma unroll
            for (int m = 0; m < 4; ++m) {
                int row = m * 16 + lrow;
                af[m] = *(const bf16x8*)((const char*)Abuf + row * 256 +
                                         ((kk * 64 + lkb) ^ ((row & 7) << 4)));
            }
            #pragma unroll
            for (int m = 0; m < 4; ++m)
                #pragma unroll
                for (int n = 0; n < 2; ++n)
                    acc1[m][n] = __builtin_amdgcn_mfma_f32_16x16x32_bf16(af[m], w1f[n][kk], acc1[m][n], 0, 0, 0);
        }
        #pragma unroll
        for (int m = 0; m < 4; ++m)
            #pragma unroll
            for (int n = 0; n < 2; ++n) {
                int fb = (wave * 32 + n * 16 + lrow) * 2;     // byte col
                #pragma unroll
                for (int i = 0; i < 4; ++i) {
                    int row = m * 16 + (lane >> 4) * 4 + i;   // D: row=(l>>4)*4+reg
                    float h = fsilu(acc1[m][n][i] + bw1[n]);
                    *(unsigned short*)((char*)Hbuf + row * 256 + (fb ^ ((row & 7) << 4))) = f2bf(h);
                }
            }
        __syncthreads();

        // ---- layer 2: H2 = silu(H1 @ W2^T + b2) -> Abuf (reuse) ----
        f32x4 acc2[4][2];
        #pragma unroll
        for (int m = 0; m < 4; ++m)
            #pragma unroll
            for (int n = 0; n < 2; ++n)
                acc2[m][n] = (f32x4){0.f, 0.f, 0.f, 0.f};
        #pragma unroll
        for (int kk = 0; kk < 4; ++kk) {
            bf16x8 af[4];
            #pragma unroll
            for (int m = 0; m < 4; ++m) {
                int row = m * 16 + lrow;
                af[m] = *(const bf16x8*)((const char*)Hbuf + row * 256 +
                                         ((kk * 64 + lkb) ^ ((row & 7) << 4)));
            }
            #pragma unroll
            for (int m = 0; m < 4; ++m)
                #pragma unroll
                for (int n = 0; n < 2; ++n)
                    acc2[m][n] = __builtin_amdgcn_mfma_f32_16x16x32_bf16(af[m], w2f[n][kk], acc2[m][n], 0, 0, 0);
        }
        #pragma unroll
        for (int m = 0; m < 4; ++m)
            #pragma unroll
            for (int n = 0; n < 2; ++n) {
                int fb = (wave * 32 + n * 16 + lrow) * 2;
                #pragma unroll
                for (int i = 0; i < 4; ++i) {
                    int row = m * 16 + (lane >> 4) * 4 + i;
                    float h = fsilu(acc2[m][n][i] + bw2[n]);
                    *(unsigned short*)((char*)Abuf + row * 256 + (fb ^ ((row & 7) << 4))) = f2bf(h);
                }
            }
        __syncthreads();

        // ---- z = H2 . Wout + bout via MFMA; pack; atomicMax scatter ----
        {
            f32x4 zac = (f32x4){0.f, 0.f, 0.f, 0.f};
            #pragma unroll
            for (int kk = 0; kk < 4; ++kk) {
                int row = wave * 16 + lrow;    // wave owns edges [16w, 16w+16)
                bf16x8 hf = *(const bf16x8*)((const char*)Abuf + row * 256 +
                                             ((kk * 64 + lkb) ^ ((row & 7) << 4)));
                zac = __builtin_amdgcn_mfma_f32_16x16x32_bf16(hf, wof[kk], zac, 0, 0, 0);
            }
            // every lane holds z for rows (lane>>4)*4 + i; 16 lanes scatter
            if ((lane & 15) < 4) {
                int i = lane & 3;
                float zv = (i == 0) ? zac[0] : (i == 1) ? zac[1] : (i == 2) ? zac[2] : zac[3];
                float z = zv + bo;
                int e  = (wave << 4) + ((lane >> 4) << 2) + i;
                int b  = t / tpb;
                int ei = (t - b * tpb) * TILE + e;
                int i0 = eidx[(size_t)(2 * b) * E + ei];
                int j0 = eidx[(size_t)(2 * b + 1) * E + ei];
                int qz = (int)((z + 36.0f) * 2048.0f + 0.5f);
                qz = qz < 0 ? 0 : (qz > 131071 ? 131071 : qz);
                unsigned int packed = (((unsigned int)(ei + 1)) << 17) | (unsigned int)qz;
                atomicMax(&out[(size_t)b * NN + (size_t)i0 * N + (size_t)j0], packed);
            }
        }
    }
}

extern "C" void kernel_launch(void* const* d_in, const int* in_sizes, int n_in,
                              void* d_out, int out_size, void* d_ws, size_t ws_size,
                              hipStream_t stream) {
    const float* edge_attr  = (const float*)d_in[0];
    const int*   edge_index = (const int*)d_in[1];
    const float* W1   = (const float*)d_in[2];
    const float* b1   = (const float*)d_in[3];
    const float* W2   = (const float*)d_in[4];
    const float* b2   = (const float*)d_in[5];
    const float* Wout = (const float*)d_in[6];
    const float* bout = (const float*)d_in[7];

    long rows = (long)in_sizes[0] / DD;        // B*E = 1,024,000
    int  E    = in_sizes[1] / 64;              // 32000 (B=32)
    int  numTiles = (int)(rows / TILE);        // 16000
    int  tpb  = E / TILE;                      // tiles per batch = 500
    int  Bb   = (int)(rows / E);               // 32
    int  N    = (int)(sqrtf((float)(out_size / Bb)) + 0.5f);   // 1000

    unsigned int* outp = (unsigned int*)d_out;
    long n = (long)out_size;

    hipMemsetAsync(d_out, 0, (size_t)out_size * sizeof(unsigned int), stream);
    mlp_scatter<<<2048, 256, 0, stream>>>(edge_attr, edge_index, W1, b1, W2, b2,
                                          Wout, bout, outp, E, numTiles, tpb, N);
    decode_log<<<2048, 256, 0, stream>>>(outp, n);
}

// Round 3
// 256.099 us; speedup vs baseline: 1.5309x; 1.0443x over previous
//
#include <hip/hip_runtime.h>
#include <stdint.h>
#include <math.h>

typedef __bf16 bf16x8 __attribute__((ext_vector_type(8)));
typedef float f32x4 __attribute__((ext_vector_type(4)));
typedef unsigned short us8 __attribute__((ext_vector_type(8)));
typedef unsigned short us4 __attribute__((ext_vector_type(4)));

#define DD 128      // feature dim
#define TILE 64     // edges per block-tile

__device__ __forceinline__ unsigned short f2bf(float f) {
    __bf16 b = (__bf16)f;                  // native v_cvt (RNE)
    return __builtin_bit_cast(unsigned short, b);
}

__device__ __forceinline__ float fsilu(float x) {
    float e = __expf(-x);
    return x * __builtin_amdgcn_rcpf(1.0f + e);
}

__device__ __forceinline__ float dec1(unsigned int u) {
    float z = (float)(u & 0x1FFFFu) * (1.0f / 2048.0f) - 36.0f;
    float s = __builtin_amdgcn_rcpf(1.0f + __expf(-z));
    return __logf(s + 1e-10f);
}

__global__ void decode_log(unsigned int* __restrict__ p, long n) {
    long i = (long)blockIdx.x * blockDim.x + threadIdx.x;
    long stride = (long)gridDim.x * blockDim.x;
    long n4 = n >> 2;
    for (long k = i; k < n4; k += stride) {
        uint4 u = ((uint4*)p)[k];
        float4 r;
        r.x = dec1(u.x); r.y = dec1(u.y); r.z = dec1(u.z); r.w = dec1(u.w);
        ((float4*)p)[k] = r;
    }
    for (long k = (n4 << 2) + i; k < n; k += stride) {
        unsigned int u = p[k];
        ((float*)p)[k] = dec1(u);
    }
}

// Block: 256 threads = 4 waves. Tile: 64 edges x 128 features, K=128.
// Wave w owns output features [32w, 32w+32) for both hidden layers.
// LDS XOR-swizzle (byte ^= (row&7)<<4) keeps ds_read_b128 conflict-free.
// T14 pipeline: tile t+1's global float4 loads are issued right after tile
// t's LDS staging, completing under the two MFMA layers (HBM latency off
// the per-tile critical path).
__global__ __launch_bounds__(256)
void mlp_scatter(const float* __restrict__ A,
                 const int* __restrict__ eidx,
                 const float* __restrict__ W1, const float* __restrict__ B1,
                 const float* __restrict__ W2, const float* __restrict__ B2,
                 const float* __restrict__ WO, const float* __restrict__ BO,
                 unsigned int* __restrict__ out,
                 int E, int numTiles, int tpb, int N)
{
    __shared__ unsigned short Abuf[TILE * DD];   // 16 KB: edge_attr bf16, reused for H2
    __shared__ unsigned short Hbuf[TILE * DD];   // 16 KB: H1 bf16

    const int tid  = threadIdx.x;
    const int lane = tid & 63;
    const int wave = tid >> 6;
    const int lrow = lane & 15;          // A-frag row / B-frag col
    const int lkb  = (lane >> 4) * 16;   // byte offset of this lane's 8-bf16 k-slice

    // ---- weight B-fragments in registers: lane holds W[f][kb..kb+7] ----
    bf16x8 w1f[2][4], w2f[2][4], wof[4];
    float bw1[2], bw2[2];
    #pragma unroll
    for (int n = 0; n < 2; ++n) {
        int f = wave * 32 + n * 16 + lrow;
        bw1[n] = B1[f];
        bw2[n] = B2[f];
        #pragma unroll
        for (int kk = 0; kk < 4; ++kk) {
            const float* p1 = W1 + f * DD + kk * 32 + (lane >> 4) * 8;
            const float* p2 = W2 + f * DD + kk * 32 + (lane >> 4) * 8;
            us8 t1, t2;
            #pragma unroll
            for (int j = 0; j < 8; ++j) { t1[j] = f2bf(p1[j]); t2[j] = f2bf(p2[j]); }
            w1f[n][kk] = __builtin_bit_cast(bf16x8, t1);
            w2f[n][kk] = __builtin_bit_cast(bf16x8, t2);
        }
    }
    // Wout broadcast fragment: every lane holds WO[k..k+7] (all 16 B-cols equal)
    #pragma unroll
    for (int kk = 0; kk < 4; ++kk) {
        const float* pw = WO + kk * 32 + (lane >> 4) * 8;
        us8 t;
        #pragma unroll
        for (int j = 0; j < 8; ++j) t[j] = f2bf(pw[j]);
        wof[kk] = __builtin_bit_cast(bf16x8, t);
    }
    const float bo = BO[0];
    const size_t NN = (size_t)N * (size_t)N;

    int t = blockIdx.x;
    if (t >= numTiles) return;

    // ---- prologue: load tile t into registers ----
    float4 v[8];
    {
        const float4* src = (const float4*)(A + (long)t * TILE * DD);
        #pragma unroll
        for (int s = 0; s < 8; ++s) v[s] = src[s * 256 + tid];
    }

    for (; t < numTiles; t += (int)gridDim.x) {
        __syncthreads();   // prev tile's z-phase reads of Abuf complete

        // ---- stage tile t from regs: fp32 -> bf16 LDS (swizzled) ----
        #pragma unroll
        for (int s = 0; s < 8; ++s) {
            int id  = s * 256 + tid;       // 2048 float4 = 64 rows x 32
            int row = id >> 5;
            int cb  = (id & 31) * 8;       // byte offset (4 ushorts)
            us4 o;
            o[0] = f2bf(v[s].x); o[1] = f2bf(v[s].y); o[2] = f2bf(v[s].z); o[3] = f2bf(v[s].w);
            *(us4*)((char*)Abuf + row * 256 + (cb ^ ((row & 7) << 4))) = o;
        }

        // ---- issue tile t+1's loads; they complete under L1/L2/z compute ----
        {
            int tn = t + (int)gridDim.x;
            if (tn >= numTiles) tn = t;    // harmless reload on last iteration
            const float4* src = (const float4*)(A + (long)tn * TILE * DD);
            #pragma unroll
            for (int s = 0; s < 8; ++s) v[s] = src[s * 256 + tid];
        }
        __syncthreads();

        // ---- layer 1: H1 = silu(A @ W1^T + b1) ----
        f32x4 acc1[4][2];
        #pragma unroll
        for (int m = 0; m < 4; ++m)
            #pragma unroll
            for (int n = 0; n < 2; ++n)
                acc1[m][n] = (f32x4){0.f, 0.f, 0.f, 0.f};
        #pragma unroll
        for (int kk = 0; kk < 4; ++kk) {
            bf16x8 af[4];
            #pragma unroll
            for (int m = 0; m < 4; ++m) {
                int row = m * 16 + lrow;
                af[m] = *(const bf16x8*)((const char*)Abuf + row * 256 +
                                         ((kk * 64 + lkb) ^ ((row & 7) << 4)));
            }
            #pragma unroll
            for (int m = 0; m < 4; ++m)
                #pragma unroll
                for (int n = 0; n < 2; ++n)
                    acc1[m][n] = __builtin_amdgcn_mfma_f32_16x16x32_bf16(af[m], w1f[n][kk], acc1[m][n], 0, 0, 0);
        }
        #pragma unroll
        for (int m = 0; m < 4; ++m)
            #pragma unroll
            for (int n = 0; n < 2; ++n) {
                int fb = (wave * 32 + n * 16 + lrow) * 2;     // byte col
                #pragma unroll
                for (int i = 0; i < 4; ++i) {
                    int row = m * 16 + (lane >> 4) * 4 + i;   // D: row=(l>>4)*4+reg
                    float h = fsilu(acc1[m][n][i] + bw1[n]);
                    *(unsigned short*)((char*)Hbuf + row * 256 + (fb ^ ((row & 7) << 4))) = f2bf(h);
                }
            }
        __syncthreads();

        // ---- layer 2: H2 = silu(H1 @ W2^T + b2) -> Abuf (reuse) ----
        f32x4 acc2[4][2];
        #pragma unroll
        for (int m = 0; m < 4; ++m)
            #pragma unroll
            for (int n = 0; n < 2; ++n)
                acc2[m][n] = (f32x4){0.f, 0.f, 0.f, 0.f};
        #pragma unroll
        for (int kk = 0; kk < 4; ++kk) {
            bf16x8 af[4];
            #pragma unroll
            for (int m = 0; m < 4; ++m) {
                int row = m * 16 + lrow;
                af[m] = *(const bf16x8*)((const char*)Hbuf + row * 256 +
                                         ((kk * 64 + lkb) ^ ((row & 7) << 4)));
            }
            #pragma unroll
            for (int m = 0; m < 4; ++m)
                #pragma unroll
                for (int n = 0; n < 2; ++n)
                    acc2[m][n] = __builtin_amdgcn_mfma_f32_16x16x32_bf16(af[m], w2f[n][kk], acc2[m][n], 0, 0, 0);
        }
        #pragma unroll
        for (int m = 0; m < 4; ++m)
            #pragma unroll
            for (int n = 0; n < 2; ++n) {
                int fb = (wave * 32 + n * 16 + lrow) * 2;
                #pragma unroll
                for (int i = 0; i < 4; ++i) {
                    int row = m * 16 + (lane >> 4) * 4 + i;
                    float h = fsilu(acc2[m][n][i] + bw2[n]);
                    *(unsigned short*)((char*)Abuf + row * 256 + (fb ^ ((row & 7) << 4))) = f2bf(h);
                }
            }
        __syncthreads();

        // ---- z = H2 . Wout + bout via MFMA; pack; atomicMax scatter ----
        {
            f32x4 zac = (f32x4){0.f, 0.f, 0.f, 0.f};
            #pragma unroll
            for (int kk = 0; kk < 4; ++kk) {
                int row = wave * 16 + lrow;    // wave owns edges [16w, 16w+16)
                bf16x8 hf = *(const bf16x8*)((const char*)Abuf + row * 256 +
                                             ((kk * 64 + lkb) ^ ((row & 7) << 4)));
                zac = __builtin_amdgcn_mfma_f32_16x16x32_bf16(hf, wof[kk], zac, 0, 0, 0);
            }
            // every lane holds z for rows (lane>>4)*4 + i; 16 lanes scatter
            if ((lane & 15) < 4) {
                int i = lane & 3;
                float zv = (i == 0) ? zac[0] : (i == 1) ? zac[1] : (i == 2) ? zac[2] : zac[3];
                float z = zv + bo;
                int e  = (wave << 4) + ((lane >> 4) << 2) + i;
                int b  = t / tpb;
                int ei = (t - b * tpb) * TILE + e;
                int i0 = eidx[(size_t)(2 * b) * E + ei];
                int j0 = eidx[(size_t)(2 * b + 1) * E + ei];
                int qz = (int)((z + 36.0f) * 2048.0f + 0.5f);
                qz = qz < 0 ? 0 : (qz > 131071 ? 131071 : qz);
                unsigned int packed = (((unsigned int)(ei + 1)) << 17) | (unsigned int)qz;
                atomicMax(&out[(size_t)b * NN + (size_t)i0 * N + (size_t)j0], packed);
            }
        }
    }
}

extern "C" void kernel_launch(void* const* d_in, const int* in_sizes, int n_in,
                              void* d_out, int out_size, void* d_ws, size_t ws_size,
                              hipStream_t stream) {
    const float* edge_attr  = (const float*)d_in[0];
    const int*   edge_index = (const int*)d_in[1];
    const float* W1   = (const float*)d_in[2];
    const float* b1   = (const float*)d_in[3];
    const float* W2   = (const float*)d_in[4];
    const float* b2   = (const float*)d_in[5];
    const float* Wout = (const float*)d_in[6];
    const float* bout = (const float*)d_in[7];

    long rows = (long)in_sizes[0] / DD;        // B*E = 1,024,000
    int  E    = in_sizes[1] / 64;              // 32000 (B=32)
    int  numTiles = (int)(rows / TILE);        // 16000
    int  tpb  = E / TILE;                      // tiles per batch = 500
    int  Bb   = (int)(rows / E);               // 32
    int  N    = (int)(sqrtf((float)(out_size / Bb)) + 0.5f);   // 1000

    unsigned int* outp = (unsigned int*)d_out;
    long n = (long)out_size;

    hipMemsetAsync(d_out, 0, (size_t)out_size * sizeof(unsigned int), stream);
    mlp_scatter<<<2048, 256, 0, stream>>>(edge_attr, edge_index, W1, b1, W2, b2,
                                          Wout, bout, outp, E, numTiles, tpb, N);
    decode_log<<<2048, 256, 0, stream>>>(outp, n);
}

// Round 4
// 233.690 us; speedup vs baseline: 1.6777x; 1.0959x over previous
//
#include <hip/hip_runtime.h>
#include <stdint.h>
#include <math.h>

typedef __bf16 bf16x8 __attribute__((ext_vector_type(8)));
typedef float f32x4 __attribute__((ext_vector_type(4)));
typedef unsigned short us8 __attribute__((ext_vector_type(8)));
typedef unsigned short us4 __attribute__((ext_vector_type(4)));

#define DD 128      // feature dim
#define TILE 64     // edges per block-tile

__device__ __forceinline__ unsigned short f2bf(float f) {
    __bf16 b = (__bf16)f;                  // native v_cvt (RNE); compiler fuses pairs to cvt_pk
    return __builtin_bit_cast(unsigned short, b);
}

__device__ __forceinline__ float fsilu(float x) {
    float e = __expf(-x);
    return x * __builtin_amdgcn_rcpf(1.0f + e);
}

__device__ __forceinline__ float dec1(unsigned int u) {
    float z = (float)(u & 0x1FFFFu) * (1.0f / 2048.0f) - 36.0f;
    float s = __builtin_amdgcn_rcpf(1.0f + __expf(-z));
    return __logf(s + 1e-10f);
}

__global__ void decode_log(unsigned int* __restrict__ p, long n) {
    long i = (long)blockIdx.x * blockDim.x + threadIdx.x;
    long stride = (long)gridDim.x * blockDim.x;
    long n4 = n >> 2;
    for (long k = i; k < n4; k += stride) {
        uint4 u = ((uint4*)p)[k];
        float4 r;
        r.x = dec1(u.x); r.y = dec1(u.y); r.z = dec1(u.z); r.w = dec1(u.w);
        ((float4*)p)[k] = r;
    }
    for (long k = (n4 << 2) + i; k < n; k += stride) {
        unsigned int u = p[k];
        ((float*)p)[k] = dec1(u);
    }
}

// Block: 256 threads = 4 waves. Tile: 64 edges x 128 features, K=128.
// SWAPPED hidden layers: C[f][e] = W[f][:]·A[e][:] with A-operand = W rows
// (wave owns f-slice [32w,32w+32) as 2 M-tiles), B-operand = edge columns
// read from the [e][f] LDS tile (b128, XOR-swizzled — identical pattern to
// the validated kernel). C-layout gives each lane 4 CONSECUTIVE f for one e
// -> packed ds_write_b64 epilogues (64 scalar u16 writes -> 16 b64 writes).
// z-phase (non-swapped, WO-broadcast B) unchanged.
__global__ __launch_bounds__(256)
void mlp_scatter(const float* __restrict__ A,
                 const int* __restrict__ eidx,
                 const float* __restrict__ W1, const float* __restrict__ B1,
                 const float* __restrict__ W2, const float* __restrict__ B2,
                 const float* __restrict__ WO, const float* __restrict__ BO,
                 unsigned int* __restrict__ out,
                 int E, int numTiles, int tpb, int N)
{
    __shared__ unsigned short Abuf[TILE * DD];   // 16 KB: edge_attr bf16, reused for H2
    __shared__ unsigned short Hbuf[TILE * DD];   // 16 KB: H1 bf16

    const int tid  = threadIdx.x;
    const int lane = tid & 63;
    const int wave = tid >> 6;
    const int lrow = lane & 15;          // frag row/col index
    const int lg   = lane >> 4;          // 4 lane-groups
    const int lkb  = lg * 16;            // byte offset of this lane's 8-bf16 k-slice

    // ---- W1/W2 A-fragments: lane holds W[f = 32w+16mt+lrow][k-slice] ----
    bf16x8 w1f[2][4], w2f[2][4], wof[4];
    float4 bias1[2], bias2[2];
    #pragma unroll
    for (int mt = 0; mt < 2; ++mt) {
        int f = wave * 32 + mt * 16 + lrow;
        bias1[mt] = *(const float4*)(B1 + wave * 32 + mt * 16 + lg * 4);
        bias2[mt] = *(const float4*)(B2 + wave * 32 + mt * 16 + lg * 4);
        #pragma unroll
        for (int kk = 0; kk < 4; ++kk) {
            const float* p1 = W1 + f * DD + kk * 32 + lg * 8;
            const float* p2 = W2 + f * DD + kk * 32 + lg * 8;
            us8 t1, t2;
            #pragma unroll
            for (int j = 0; j < 8; ++j) { t1[j] = f2bf(p1[j]); t2[j] = f2bf(p2[j]); }
            w1f[mt][kk] = __builtin_bit_cast(bf16x8, t1);
            w2f[mt][kk] = __builtin_bit_cast(bf16x8, t2);
        }
    }
    // Wout broadcast B-fragment (z-phase, non-swapped): lane holds WO[k..k+7]
    #pragma unroll
    for (int kk = 0; kk < 4; ++kk) {
        const float* pw = WO + kk * 32 + lg * 8;
        us8 t;
        #pragma unroll
        for (int j = 0; j < 8; ++j) t[j] = f2bf(pw[j]);
        wof[kk] = __builtin_bit_cast(bf16x8, t);
    }
    const float bo = BO[0];
    const size_t NN = (size_t)N * (size_t)N;

    int t = blockIdx.x;
    if (t >= numTiles) return;

    // ---- prologue: load tile t into registers ----
    float4 v[8];
    {
        const float4* src = (const float4*)(A + (long)t * TILE * DD);
        #pragma unroll
        for (int s = 0; s < 8; ++s) v[s] = src[s * 256 + tid];
    }

    for (; t < numTiles; t += (int)gridDim.x) {
        // ---- hoist eidx loads for this tile's scatter (latency off the tail) ----
        int i0 = 0, j0 = 0, sb = 0, sei = 0;
        if (lrow < 4) {
            int e  = (wave << 4) + (lg << 2) + (lane & 3);
            sb  = t / tpb;
            sei = (t - sb * tpb) * TILE + e;
            i0 = eidx[(size_t)(2 * sb) * E + sei];
            j0 = eidx[(size_t)(2 * sb + 1) * E + sei];
        }

        __syncthreads();   // prev tile's z-phase reads of Abuf complete

        // ---- stage tile t from regs: fp32 -> bf16 LDS (swizzled) ----
        #pragma unroll
        for (int s = 0; s < 8; ++s) {
            int id  = s * 256 + tid;       // 2048 float4 = 64 rows x 32
            int row = id >> 5;
            int cb  = (id & 31) * 8;       // byte offset (4 ushorts)
            us4 o;
            o[0] = f2bf(v[s].x); o[1] = f2bf(v[s].y); o[2] = f2bf(v[s].z); o[3] = f2bf(v[s].w);
            *(us4*)((char*)Abuf + row * 256 + (cb ^ ((row & 7) << 4))) = o;
        }

        // ---- issue tile t+1's loads; complete under the MFMA layers ----
        {
            int tn = t + (int)gridDim.x;
            if (tn >= numTiles) tn = t;
            const float4* src = (const float4*)(A + (long)tn * TILE * DD);
            #pragma unroll
            for (int s = 0; s < 8; ++s) v[s] = src[s * 256 + tid];
        }
        __syncthreads();

        // ---- layer 1 (swapped): C1[f][e], f-slice per wave ----
        f32x4 acc1[2][4];
        #pragma unroll
        for (int mt = 0; mt < 2; ++mt)
            #pragma unroll
            for (int nt = 0; nt < 4; ++nt)
                acc1[mt][nt] = (f32x4){0.f, 0.f, 0.f, 0.f};
        #pragma unroll
        for (int kk = 0; kk < 4; ++kk) {
            bf16x8 ef[4];
            #pragma unroll
            for (int nt = 0; nt < 4; ++nt) {
                int e = nt * 16 + lrow;
                ef[nt] = *(const bf16x8*)((const char*)Abuf + e * 256 +
                                          ((kk * 64 + lkb) ^ ((e & 7) << 4)));
            }
            #pragma unroll
            for (int mt = 0; mt < 2; ++mt)
                #pragma unroll
                for (int nt = 0; nt < 4; ++nt)
                    acc1[mt][nt] = __builtin_amdgcn_mfma_f32_16x16x32_bf16(w1f[mt][kk], ef[nt], acc1[mt][nt], 0, 0, 0);
        }
        // epilogue: 4 consecutive f per lane -> packed b64 writes into Hbuf[e][f]
        #pragma unroll
        for (int mt = 0; mt < 2; ++mt)
            #pragma unroll
            for (int nt = 0; nt < 4; ++nt) {
                int e  = nt * 16 + lrow;
                int fb = (wave * 32 + mt * 16 + lg * 4) * 2;   // byte col of f0
                us4 o;
                #pragma unroll
                for (int i = 0; i < 4; ++i) {
                    float h = fsilu(acc1[mt][nt][i] + bias1[mt][i]);
                    o[i] = f2bf(h);
                }
                *(us4*)((char*)Hbuf + e * 256 + (fb ^ ((e & 7) << 4))) = o;
            }
        __syncthreads();

        // ---- layer 2 (swapped): reads H1 from Hbuf, writes H2 -> Abuf ----
        f32x4 acc2[2][4];
        #pragma unroll
        for (int mt = 0; mt < 2; ++mt)
            #pragma unroll
            for (int nt = 0; nt < 4; ++nt)
                acc2[mt][nt] = (f32x4){0.f, 0.f, 0.f, 0.f};
        #pragma unroll
        for (int kk = 0; kk < 4; ++kk) {
            bf16x8 ef[4];
            #pragma unroll
            for (int nt = 0; nt < 4; ++nt) {
                int e = nt * 16 + lrow;
                ef[nt] = *(const bf16x8*)((const char*)Hbuf + e * 256 +
                                          ((kk * 64 + lkb) ^ ((e & 7) << 4)));
            }
            #pragma unroll
            for (int mt = 0; mt < 2; ++mt)
                #pragma unroll
                for (int nt = 0; nt < 4; ++nt)
                    acc2[mt][nt] = __builtin_amdgcn_mfma_f32_16x16x32_bf16(w2f[mt][kk], ef[nt], acc2[mt][nt], 0, 0, 0);
        }
        #pragma unroll
        for (int mt = 0; mt < 2; ++mt)
            #pragma unroll
            for (int nt = 0; nt < 4; ++nt) {
                int e  = nt * 16 + lrow;
                int fb = (wave * 32 + mt * 16 + lg * 4) * 2;
                us4 o;
                #pragma unroll
                for (int i = 0; i < 4; ++i) {
                    float h = fsilu(acc2[mt][nt][i] + bias2[mt][i]);
                    o[i] = f2bf(h);
                }
                *(us4*)((char*)Abuf + e * 256 + (fb ^ ((e & 7) << 4))) = o;
            }
        __syncthreads();

        // ---- z = H2 . Wout + bout via MFMA (non-swapped, WO broadcast) ----
        {
            f32x4 zac = (f32x4){0.f, 0.f, 0.f, 0.f};
            #pragma unroll
            for (int kk = 0; kk < 4; ++kk) {
                int row = wave * 16 + lrow;    // wave owns edges [16w, 16w+16)
                bf16x8 hf = *(const bf16x8*)((const char*)Abuf + row * 256 +
                                             ((kk * 64 + lkb) ^ ((row & 7) << 4)));
                zac = __builtin_amdgcn_mfma_f32_16x16x32_bf16(hf, wof[kk], zac, 0, 0, 0);
            }
            // lane holds z for edges (lg)*4 + i; lanes with lrow<4 scatter
            if (lrow < 4) {
                int i = lane & 3;
                float zv = (i == 0) ? zac[0] : (i == 1) ? zac[1] : (i == 2) ? zac[2] : zac[3];
                float z = zv + bo;
                int qz = (int)((z + 36.0f) * 2048.0f + 0.5f);
                qz = qz < 0 ? 0 : (qz > 131071 ? 131071 : qz);
                unsigned int packed = (((unsigned int)(sei + 1)) << 17) | (unsigned int)qz;
                atomicMax(&out[(size_t)sb * NN + (size_t)i0 * N + (size_t)j0], packed);
            }
        }
    }
}

extern "C" void kernel_launch(void* const* d_in, const int* in_sizes, int n_in,
                              void* d_out, int out_size, void* d_ws, size_t ws_size,
                              hipStream_t stream) {
    const float* edge_attr  = (const float*)d_in[0];
    const int*   edge_index = (const int*)d_in[1];
    const float* W1   = (const float*)d_in[2];
    const float* b1   = (const float*)d_in[3];
    const float* W2   = (const float*)d_in[4];
    const float* b2   = (const float*)d_in[5];
    const float* Wout = (const float*)d_in[6];
    const float* bout = (const float*)d_in[7];

    long rows = (long)in_sizes[0] / DD;        // B*E = 1,024,000
    int  E    = in_sizes[1] / 64;              // 32000 (B=32)
    int  numTiles = (int)(rows / TILE);        // 16000
    int  tpb  = E / TILE;                      // tiles per batch = 500
    int  Bb   = (int)(rows / E);               // 32
    int  N    = (int)(sqrtf((float)(out_size / Bb)) + 0.5f);   // 1000

    unsigned int* outp = (unsigned int*)d_out;
    long n = (long)out_size;

    hipMemsetAsync(d_out, 0, (size_t)out_size * sizeof(unsigned int), stream);
    mlp_scatter<<<2048, 256, 0, stream>>>(edge_attr, edge_index, W1, b1, W2, b2,
                                          Wout, bout, outp, E, numTiles, tpb, N);
    decode_log<<<2048, 256, 0, stream>>>(outp, n);
}